// Round 5
// baseline (534.755 us; speedup 1.0000x reference)
//
#include <hip/hip_runtime.h>

#define NTOK 16384
#define DM 1024
#define BM 128
#define BN 128
#define BK 64

typedef _Float16 h16;
typedef __attribute__((ext_vector_type(8))) _Float16 half8;
typedef __attribute__((ext_vector_type(4))) _Float16 half4;
typedef __attribute__((ext_vector_type(4))) float floatx4;

// Swizzled LDS byte offset for a [128 rows][64 fp16 cols] plane (row stride 128B).
// XOR 16B-chunk index with (row&7) — conflict-free (R1-R3: SQ_LDS_BANK_CONFLICT=0).
__device__ __forceinline__ unsigned lds_off(unsigned r, unsigned c) {
  return r * 128u + ((((c >> 3) ^ r) & 7u) << 4) + (c & 7u) * 2u;
}

// fp32x4 -> fp16x4 packed as uint2 (8B)
__device__ __forceinline__ uint2 f4h4(float4 f) {
  unsigned short a = __builtin_bit_cast(unsigned short, (h16)f.x);
  unsigned short b = __builtin_bit_cast(unsigned short, (h16)f.y);
  unsigned short c = __builtin_bit_cast(unsigned short, (h16)f.z);
  unsigned short d = __builtin_bit_cast(unsigned short, (h16)f.w);
  uint2 r;
  r.x = (unsigned)a | ((unsigned)b << 16);
  r.y = (unsigned)c | ((unsigned)d << 16);
  return r;
}

// async global->LDS, 16B/lane; LDS dest is wave-uniform base + lane*16 (HW rule)
__device__ __forceinline__ void gload16(const h16* g, char* l) {
  __builtin_amdgcn_global_load_lds((const __attribute__((address_space(1))) unsigned*)g,
                                   (__attribute__((address_space(3))) unsigned*)l, 16, 0, 0);
}

// one K-tile of MFMA: 2 ks-substeps x (8 ds_read_b128 + 16 mfma) per wave
__device__ __forceinline__ void mfma_tile(const char* Ap, const char* Bp, int wm, int wn,
                                          int fr, int fq, floatx4 (&acc)[4][4]) {
#pragma unroll
  for (int ks = 0; ks < 2; ++ks) {
    half8 af[4], bf[4];
#pragma unroll
    for (int i = 0; i < 4; ++i) {
      af[i] = *(const half8*)(Ap + lds_off(wm + i * 16 + fr, ks * 32 + fq * 8));
      bf[i] = *(const half8*)(Bp + lds_off(wn + i * 16 + fr, ks * 32 + fq * 8));
    }
#pragma unroll
    for (int mi = 0; mi < 4; ++mi)
#pragma unroll
      for (int ni = 0; ni < 4; ++ni)
        acc[mi][ni] = __builtin_amdgcn_mfma_f32_16x16x32_f16(af[mi], bf[ni], acc[mi][ni], 0, 0, 0);
  }
}

// ---------- pipelined GEMM: C[16384,1024] = A @ W^T + bias ----------
// 128x128 tile, BK=64, 4 waves (2x2), double-buffered LDS (T3-min 2-phase):
// prefetch tile t+1 (issue loads) BEFORE computing tile t; one barrier/K-step.
// AHALF: A fp16 via global_load_lds. !AHALF: A fp32 via regs (T14: issue early,
// cvt+ds_write late) -- fuses the fp32->fp16 conversion into the GEMM.
template <bool AHALF, bool OHALF>
__global__ __launch_bounds__(256, 2) void gemm_p(const void* __restrict__ Aptr,
                                                 const h16* __restrict__ W,
                                                 const float* __restrict__ bias,
                                                 void* __restrict__ Cptr) {
  __shared__ __align__(16) char smem[65536];  // buf0: A@0 B@16K; buf1: A@32K B@48K

  const int tid = threadIdx.x;

  // XCD-aware bijective swizzle (R2/R3-verified): each XCD owns 16 consecutive
  // row-panels; a panel's 8 column-blocks stay on one XCD (A-panel L2-resident).
  const int bid = (int)(blockIdx.x + gridDim.x * blockIdx.y);
  const int xcd = bid & 7, ch = bid >> 3;
  const int m0 = (xcd * 16 + (ch >> 3)) * BM;
  const int n0 = (ch & 7) * BN;

  const int lane = tid & 63;
  const int wave = tid >> 6;
  const int wm = (wave >> 1) * 64;
  const int wn = (wave & 1) * 64;
  const int fr = lane & 15;
  const int fq = lane >> 4;

  floatx4 acc[4][4] = {};

  // gload_lds source map (pre-swizzled global col-chunk; linear LDS dest):
  // wave w issue i covers rows w*32+i*8..+8; lane row lr=lane>>3, chunk lc=(lane&7)^lr.
  const int lr = lane >> 3;
  const int lc = (lane & 7) ^ lr;
  const h16* wg = W + (long)(n0 + wave * 32 + lr) * DM + lc * 8;
  const h16* agh = AHALF ? (const h16*)Aptr + (long)(m0 + wave * 32 + lr) * DM + lc * 8 : nullptr;

  // fp32-A reg-staging map: 16 rows x 16 float4 per pass, 8 passes (rows rb+16i)
  const int rb = tid >> 4, c4 = tid & 15;
  const float* agf = AHALF ? nullptr : (const float*)Aptr + (long)(m0 + rb) * DM + c4 * 4;
  float4 areg[8];

  auto issueB = [&](int kt, int buf) {
    char* bl = smem + 16384 + buf * 32768 + wave * 4096;
#pragma unroll
    for (int i = 0; i < 4; ++i) gload16(wg + (long)(i * 8) * DM + kt, bl + i * 1024);
  };
  auto issueA_h = [&](int kt, int buf) {
    char* al = smem + buf * 32768 + wave * 4096;
#pragma unroll
    for (int i = 0; i < 4; ++i) gload16(agh + (long)(i * 8) * DM + kt, al + i * 1024);
  };
  auto loadA_f = [&](int kt) {
#pragma unroll
    for (int i = 0; i < 8; ++i) areg[i] = *(const float4*)(agf + (long)(i * 16) * DM + kt);
  };
  auto writeA_f = [&](int buf) {  // compiler inserts vmcnt waits before areg use
    char* al = smem + buf * 32768;
#pragma unroll
    for (int i = 0; i < 8; ++i)
      *(uint2*)(al + lds_off(rb + i * 16, c4 * 4)) = f4h4(areg[i]);
  };

  // ---- prologue: stage tile 0 into buf0 ----
  issueB(0, 0);
  if constexpr (AHALF) {
    issueA_h(0, 0);
  } else {
    loadA_f(0);
    writeA_f(0);
  }
  __syncthreads();  // drains gloads (vmcnt) + ds_writes (lgkm)

  // ---- main loop: prefetch t+1, compute t ----
  int cur = 0;
  for (int kt = BK; kt < DM; kt += BK) {
    issueB(kt, cur ^ 1);
    if constexpr (AHALF) {
      issueA_h(kt, cur ^ 1);
      mfma_tile(smem + cur * 32768, smem + 16384 + cur * 32768, wm, wn, fr, fq, acc);
    } else {
      loadA_f(kt);  // T14: issue early...
      mfma_tile(smem + cur * 32768, smem + 16384 + cur * 32768, wm, wn, fr, fq, acc);
      writeA_f(cur ^ 1);  // ...write late (loads aged under MFMA)
    }
    __syncthreads();
    cur ^= 1;
  }
  mfma_tile(smem + cur * 32768, smem + 16384 + cur * 32768, wm, wn, fr, fq, acc);

  // ---- epilogue: C/D layout col=lane&15, row=(lane>>4)*4+reg (R1-R3 verified) ----
#pragma unroll
  for (int ni = 0; ni < 4; ++ni) {
    const int col = n0 + wn + ni * 16 + fr;
    const float bv = bias[col];
#pragma unroll
    for (int mi = 0; mi < 4; ++mi) {
      const int row0 = m0 + wm + mi * 16 + fq * 4;
#pragma unroll
      for (int j = 0; j < 4; ++j) {
        const float val = acc[mi][ni][j] + bv;
        if constexpr (OHALF)
          ((h16*)Cptr)[(long)(row0 + j) * DM + col] = (h16)val;
        else
          ((float*)Cptr)[(long)(row0 + j) * DM + col] = val;
      }
    }
  }
}

// ---------- fp32 -> fp16 weight pre-convert (8 MB total, ~5 us) ----------
__global__ __launch_bounds__(256) void cvtW(const float* __restrict__ a, const float* __restrict__ b,
                                            const float* __restrict__ c, const float* __restrict__ e,
                                            h16* __restrict__ oa, h16* __restrict__ ob,
                                            h16* __restrict__ oc, h16* __restrict__ oe) {
  const long i = ((long)blockIdx.x * 256 + threadIdx.x) * 8;
  const float* s = blockIdx.y == 0 ? a : blockIdx.y == 1 ? b : blockIdx.y == 2 ? c : e;
  h16* d = blockIdx.y == 0 ? oa : blockIdx.y == 1 ? ob : blockIdx.y == 2 ? oc : oe;
  float4 f0 = *(const float4*)(s + i);
  float4 f1 = *(const float4*)(s + i + 4);
  half8 h;
  h[0] = (h16)f0.x; h[1] = (h16)f0.y; h[2] = (h16)f0.z; h[3] = (h16)f0.w;
  h[4] = (h16)f1.x; h[5] = (h16)f1.y; h[6] = (h16)f1.z; h[7] = (h16)f1.w;
  *(half8*)(d + i) = h;
}

// ---------- per-token attention over the HEADS axis (16x16 per token), fp16 I/O ----------
__global__ __launch_bounds__(256) void attn_heads_h(h16* __restrict__ Q,
                                                    const h16* __restrict__ K,
                                                    const h16* __restrict__ V) {
  __shared__ float qs[16][68];
  __shared__ float ks[16][68];
  __shared__ float vs[16][68];
  __shared__ float pw[16][17];
  const int t = blockIdx.x;
  const int tid = threadIdx.x;
  const long base = (long)t * DM + tid * 4;
  const int h = tid >> 4;
  const int d0 = (tid & 15) * 4;

  {
    half4 fq = *(const half4*)(Q + base);
    half4 fk = *(const half4*)(K + base);
    half4 fv = *(const half4*)(V + base);
    *(float4*)&qs[h][d0] = make_float4((float)fq[0], (float)fq[1], (float)fq[2], (float)fq[3]);
    *(float4*)&ks[h][d0] = make_float4((float)fk[0], (float)fk[1], (float)fk[2], (float)fk[3]);
    *(float4*)&vs[h][d0] = make_float4((float)fv[0], (float)fv[1], (float)fv[2], (float)fv[3]);
  }
  __syncthreads();

  const int g = tid & 15;
  float s = 0.f;
#pragma unroll
  for (int d = 0; d < 64; ++d) s += qs[h][d] * ks[g][d];
  s *= 0.125f;

  float mx = s;
#pragma unroll
  for (int off = 8; off > 0; off >>= 1) mx = fmaxf(mx, __shfl_xor(mx, off, 16));
  float e = __expf(s - mx);
  float den = e;
#pragma unroll
  for (int off = 8; off > 0; off >>= 1) den += __shfl_xor(den, off, 16);
  pw[h][g] = e / den;
  __syncthreads();

  float4 o = make_float4(0.f, 0.f, 0.f, 0.f);
#pragma unroll
  for (int g2 = 0; g2 < 16; ++g2) {
    const float p = pw[h][g2];
    o.x += p * vs[g2][d0 + 0];
    o.y += p * vs[g2][d0 + 1];
    o.z += p * vs[g2][d0 + 2];
    o.w += p * vs[g2][d0 + 3];
  }
  half4 oh;
  oh[0] = (h16)o.x; oh[1] = (h16)o.y; oh[2] = (h16)o.z; oh[3] = (h16)o.w;
  *(half4*)(Q + base) = oh;  // in-place over Q (fully staged to LDS above)
}

// ---------- launch ----------
extern "C" void kernel_launch(void* const* d_in, const int* in_sizes, int n_in,
                              void* d_out, int out_size, void* d_ws, size_t ws_size,
                              hipStream_t stream) {
  const float* q  = (const float*)d_in[0];
  const float* k  = (const float*)d_in[1];
  const float* v  = (const float*)d_in[2];
  const float* Wq = (const float*)d_in[3];
  const float* bq = (const float*)d_in[4];
  const float* Wk = (const float*)d_in[5];
  const float* bk = (const float*)d_in[6];
  const float* Wv = (const float*)d_in[7];
  const float* bv = (const float*)d_in[8];
  const float* Wo = (const float*)d_in[9];
  const float* bo = (const float*)d_in[10];

  const size_t WE = (size_t)DM * DM;
  h16* Wqh = (h16*)d_ws;           // 2 MB each
  h16* Wkh = Wqh + WE;
  h16* Wvh = Wkh + WE;
  h16* Woh = Wvh + WE;
  h16* Qp  = Woh + WE;             // 32 MB
  h16* Kp  = Qp + (size_t)NTOK * DM;
  h16* Vp  = Kp + (size_t)NTOK * DM;  // total 104 MB

  dim3 ggrid(DM / BN, NTOK / BM);  // (8, 128)
  dim3 gblk(256);

  cvtW<<<dim3(WE / (256 * 8), 4), gblk, 0, stream>>>(Wq, Wk, Wv, Wo, Wqh, Wkh, Wvh, Woh);

  gemm_p<false, true><<<ggrid, gblk, 0, stream>>>(q, Wqh, bq, Qp);
  gemm_p<false, true><<<ggrid, gblk, 0, stream>>>(k, Wkh, bk, Kp);
  gemm_p<false, true><<<ggrid, gblk, 0, stream>>>(v, Wvh, bv, Vp);
  attn_heads_h<<<dim3(NTOK), gblk, 0, stream>>>(Qp, Kp, Vp);
  gemm_p<true, false><<<ggrid, gblk, 0, stream>>>(Qp, Woh, bo, (float*)d_out);
}